// Round 1
// baseline (69.660 us; speedup 1.0000x reference)
//
#include <hip/hip_runtime.h>
#include <math.h>

// Problem constants (match reference)
#define BN 32
#define RR 13
#define CC 13
#define AA 5
#define KK 20
#define CELLSZ 25           // K + 5
#define NN (RR * CC * AA)   // 845
#define THRESH 0.5f
#define NMS_TH 0.4f

__device__ __forceinline__ float sigmoidf_(float x) {
    return 1.0f / (1.0f + expf(-x));
}

// One thread per (b, n) cell: decode box, softmax over classes, threshold.
// Writes all 25 output floats for the cell (NMS kernel later zeroes suppressed).
__global__ void decode_kernel(const float* __restrict__ x,
                              const float* __restrict__ bias,
                              float* __restrict__ out) {
    int idx = blockIdx.x * blockDim.x + threadIdx.x;
    if (idx >= BN * NN) return;
    int b = idx / NN;
    int n = idx % NN;
    int r = n / (CC * AA);
    int rem = n % (CC * AA);
    int c = rem / AA;
    int a = rem % AA;

    // x layout: (B, R, C, A*CELL)
    const float* t = x + (((size_t)(b * RR + r) * CC + c) * AA + a) * CELLSZ;

    float t0 = t[0], t1 = t[1], t2 = t[2], t3 = t[3], t4 = t[4];
    float bx = (sigmoidf_(t0) + (float)c) / (float)CC;
    float by = (sigmoidf_(t1) + (float)r) / (float)RR;
    float bw = expf(t2) * bias[2 * a] / (float)RR;      // bias[0::2][a]
    float bh = expf(t3) * bias[2 * a + 1] / (float)CC;  // bias[1::2][a]
    float obj = sigmoidf_(t4);

    // softmax over 20 class logits (max-subtract, like jax.nn.softmax)
    float cl[KK];
    float m = t[5];
#pragma unroll
    for (int k = 1; k < KK; ++k) m = fmaxf(m, t[5 + k]);
    float s = 0.0f;
#pragma unroll
    for (int k = 0; k < KK; ++k) { cl[k] = expf(t[5 + k] - m); s += cl[k]; }

    float* o = out + (size_t)(b * NN + n) * CELLSZ;
    o[0] = bx; o[1] = by; o[2] = bw; o[3] = bh; o[4] = obj;
#pragma unroll
    for (int k = 0; k < KK; ++k) {
        float p = obj * (cl[k] / s);
        o[5 + k] = (p > THRESH) ? p : 0.0f;
    }
}

// One block per (b, k): greedy NMS over the N=845 boxes for that class.
// state: 0 = pending candidate (score > THRESH), 1 = removed/non-candidate, 2 = kept
__global__ void nms_kernel(float* __restrict__ out) {
    __shared__ float sx1[NN], sy1[NN], sx2[NN], sy2[NN], sar[NN], ssc[NN];
    __shared__ unsigned char st[NN];
    __shared__ float red_s[256];
    __shared__ int   red_i[256];

    int b = blockIdx.x / KK;
    int k = blockIdx.x % KK;
    int tid = threadIdx.x;

    // Stage boxes + this class's scores into LDS (boxes recomputed exactly as
    // the reference: x1 = bx - bw*0.5, x2 = x1 + bw, area = bw*bh).
    for (int n = tid; n < NN; n += 256) {
        const float* o = out + (size_t)(b * NN + n) * CELLSZ;
        float bx = o[0], by = o[1], bw = o[2], bh = o[3];
        float x1 = bx - bw * 0.5f;
        float y1 = by - bh * 0.5f;
        sx1[n] = x1;
        sy1[n] = y1;
        sx2[n] = x1 + bw;
        sy2[n] = y1 + bh;
        sar[n] = bw * bh;
        float sc = o[5 + k];
        ssc[n] = sc;
        st[n] = (sc > THRESH) ? 0 : 1;
    }
    __syncthreads();

    // Greedy loop: pick max-score pending (lowest index on ties — matches
    // jnp.argsort stability), keep it, suppress pending boxes with IoU > 0.4.
    while (true) {
        float best = -1.0f;
        int bi = 0x7fffffff;
        for (int n = tid; n < NN; n += 256) {
            if (st[n] == 0) {
                float sc = ssc[n];
                if (sc > best || (sc == best && n < bi)) { best = sc; bi = n; }
            }
        }
        red_s[tid] = best;
        red_i[tid] = bi;
        __syncthreads();
#pragma unroll
        for (int off = 128; off > 0; off >>= 1) {
            if (tid < off) {
                float so = red_s[tid + off];
                int   io = red_i[tid + off];
                if (so > red_s[tid] || (so == red_s[tid] && io < red_i[tid])) {
                    red_s[tid] = so;
                    red_i[tid] = io;
                }
            }
            __syncthreads();
        }
        float bsc = red_s[0];
        int   sel = red_i[0];
        __syncthreads();   // red_* free for next iteration; all threads agree

        if (bsc < 0.0f) break;   // uniform exit: no pending candidates left

        if (tid == 0) st[sel] = 2;   // keep (visible after loop-end barrier)

        float X1 = sx1[sel], Y1 = sy1[sel], X2 = sx2[sel], Y2 = sy2[sel];
        float AR = sar[sel];
        for (int n = tid; n < NN; n += 256) {
            if (n != sel && st[n] == 0) {
                float iw = fmaxf(0.0f, fminf(X2, sx2[n]) - fmaxf(X1, sx1[n]));
                float ih = fmaxf(0.0f, fminf(Y2, sy2[n]) - fmaxf(Y1, sy1[n]));
                float inter = iw * ih;
                float uni = AR + sar[n] - inter;
                float iou = inter / fmaxf(uni, 1e-9f);
                if (iou > NMS_TH) st[n] = 1;
            }
        }
        __syncthreads();
    }

    // Zero the suppressed candidates' scores (non-candidates already 0).
    for (int n = tid; n < NN; n += 256) {
        if (ssc[n] > THRESH && st[n] != 2) {
            out[(size_t)(b * NN + n) * CELLSZ + 5 + k] = 0.0f;
        }
    }
}

extern "C" void kernel_launch(void* const* d_in, const int* in_sizes, int n_in,
                              void* d_out, int out_size, void* d_ws, size_t ws_size,
                              hipStream_t stream) {
    const float* x    = (const float*)d_in[0];
    const float* bias = (const float*)d_in[1];
    float* out = (float*)d_out;

    decode_kernel<<<(BN * NN + 255) / 256, 256, 0, stream>>>(x, bias, out);
    nms_kernel<<<BN * KK, 256, 0, stream>>>(out);
}